// Round 1
// baseline (373.408 us; speedup 1.0000x reference)
//
#include <hip/hip_runtime.h>
#include <hip/hip_bf16.h>
#include <cstdint>
#include <cmath>

#define T_TOK 8192
#define HD 1024
#define ID 512
#define NE 8
#define BM 128
#define BN 128
#define BK 32
#define MAXMT (T_TOK / BM)   // 64

typedef __attribute__((ext_vector_type(8))) short short8;
typedef __attribute__((ext_vector_type(4))) float f32x4;

__device__ __forceinline__ unsigned short f2bf(float f) {
  union { float f; unsigned int u; } v; v.f = f;
  unsigned int u = v.u;
  u += 0x7fffu + ((u >> 16) & 1u);   // RNE
  return (unsigned short)(u >> 16);
}

#if __has_builtin(__builtin_amdgcn_global_load_lds)
#define HAVE_GLDS 1
#endif

// Global->LDS 16B/lane stage. Async path: LDS dest is wave-uniform base + lane*16.
__device__ __forceinline__ void stage16(const ushort* __restrict__ g,
                                        ushort* lds_wave_base, int lane) {
#ifdef HAVE_GLDS
  __builtin_amdgcn_global_load_lds((const __attribute__((address_space(1))) void*)g,
                                   (__attribute__((address_space(3))) void*)lds_wave_base,
                                   16, 0, 0);
#else
  *(uint4*)(lds_wave_base + (size_t)lane * 8) = *(const uint4*)g;
#endif
}

// ---------------- router: logits, argmax, sigmoid ----------------
__global__ __launch_bounds__(256) void k_router(const float* __restrict__ x,
                                                const float* __restrict__ gw,
                                                int* __restrict__ sel,
                                                float* __restrict__ rw,
                                                int* __restrict__ cnt) {
  if (blockIdx.x == 0 && threadIdx.x < NE) cnt[threadIdx.x] = 0;  // used only by later kernels
  int wv = threadIdx.x >> 6, lane = threadIdx.x & 63;
  int t = blockIdx.x * 4 + wv;
  const float4* xr = (const float4*)(x + (size_t)t * HD);
  double acc[NE];
#pragma unroll
  for (int e = 0; e < NE; e++) acc[e] = 0.0;
#pragma unroll
  for (int j = 0; j < 4; j++) {
    float4 xv = xr[lane + 64 * j];
#pragma unroll
    for (int e = 0; e < NE; e++) {
      float4 wv4 = ((const float4*)(gw + e * HD))[lane + 64 * j];
      acc[e] += (double)xv.x * wv4.x + (double)xv.y * wv4.y +
                (double)xv.z * wv4.z + (double)xv.w * wv4.w;
    }
  }
#pragma unroll
  for (int e = 0; e < NE; e++)
    for (int off = 32; off >= 1; off >>= 1)
      acc[e] += __shfl_xor(acc[e], off);
  if (lane == 0) {
    double best = acc[0]; int bi = 0;
#pragma unroll
    for (int e = 1; e < NE; e++) if (acc[e] > best) { best = acc[e]; bi = e; }
    sel[t] = bi;
    rw[t] = (float)(1.0 / (1.0 + exp(-best)));
  }
}

__global__ void k_count(const int* __restrict__ sel, int* __restrict__ cnt,
                        int* __restrict__ rank) {
  int t = blockIdx.x * 256 + threadIdx.x;
  rank[t] = atomicAdd(&cnt[sel[t]], 1);
}

__global__ void k_perm(const int* __restrict__ sel, const int* __restrict__ cnt,
                       const int* __restrict__ rank, int* __restrict__ perm) {
  int t = blockIdx.x * 256 + threadIdx.x;
  int s = sel[t];
  int off = 0;
#pragma unroll
  for (int e = 0; e < NE; e++) off += (e < s) ? cnt[e] : 0;
  perm[off + rank[t]] = t;
}

// gather + routing-weight scale + fp32->bf16
__global__ __launch_bounds__(256) void k_gather(const float* __restrict__ x,
                                                const float* __restrict__ rw,
                                                const int* __restrict__ perm,
                                                ushort* __restrict__ xs) {
  int p = blockIdx.x;
  int t = perm[p];
  float s = rw[t];
  const float4* src = (const float4*)(x + (size_t)t * HD);
  ushort4* dst = (ushort4*)(xs + (size_t)p * HD);
  float4 v = src[threadIdx.x];
  ushort4 o;
  o.x = f2bf(v.x * s); o.y = f2bf(v.y * s); o.z = f2bf(v.z * s); o.w = f2bf(v.w * s);
  dst[threadIdx.x] = o;
}

// cast all three expert weight tensors fp32->bf16
__global__ __launch_bounds__(256) void k_cast(const float4* __restrict__ a,
                                              const float4* __restrict__ b,
                                              const float4* __restrict__ c,
                                              ushort4* __restrict__ oa,
                                              ushort4* __restrict__ ob,
                                              ushort4* __restrict__ oc) {
  int i = blockIdx.x * 256 + threadIdx.x;
  float4 v; ushort4 r;
  v = a[i]; r.x = f2bf(v.x); r.y = f2bf(v.y); r.z = f2bf(v.z); r.w = f2bf(v.w); oa[i] = r;
  v = b[i]; r.x = f2bf(v.x); r.y = f2bf(v.y); r.z = f2bf(v.z); r.w = f2bf(v.w); ob[i] = r;
  v = c[i]; r.x = f2bf(v.x); r.y = f2bf(v.y); r.z = f2bf(v.z); r.w = f2bf(v.w); oc[i] = r;
}

// ---------------- fused gate+up GEMM -> h = u * silu(g) ----------------
__global__ __launch_bounds__(256) void k_gemm_gu(const ushort* __restrict__ xs,
                                                 const ushort* __restrict__ wg,
                                                 const ushort* __restrict__ wu,
                                                 const int* __restrict__ cnt,
                                                 ushort* __restrict__ h) {
  int e = blockIdx.x / MAXMT;
  int mt = blockIdx.x % MAXMT;
  int cnte = cnt[e];
  if (mt * BM >= cnte) return;
  int off = 0;
#pragma unroll
  for (int i = 0; i < NE; i++) off += (i < e) ? cnt[i] : 0;
  int m0 = off + mt * BM;
  int rv = cnte - mt * BM; if (rv > BM) rv = BM;
  int n0 = blockIdx.y * BN;

  __shared__ __align__(16) ushort As[BM * BK];
  __shared__ __align__(16) ushort Bg[BN * BK];
  __shared__ __align__(16) ushort Bu[BN * BK];

  int tid = threadIdx.x;
  int wv = tid >> 6, lane = tid & 63;
  int wm = wv >> 1, wn = wv & 1;

  f32x4 accg[4][4] = {};
  f32x4 accu[4][4] = {};

  int srow0 = wv * 16 + (lane >> 2);
  int scol = (lane & 3) * 8;
  const ushort* wgE = wg + (size_t)e * ID * HD;
  const ushort* wuE = wu + (size_t)e * ID * HD;
  int frow = lane & 15;
  int fk = (lane >> 4) * 8;

  for (int k0 = 0; k0 < HD; k0 += BK) {
    __syncthreads();
#pragma unroll
    for (int i = 0; i < 2; i++) {
      int row = i * 64 + srow0;
      int ldsoff = (i * 64 + wv * 16) * BK;
      stage16(xs  + (size_t)(m0 + row) * HD + k0 + scol, &As[ldsoff], lane);
      stage16(wgE + (size_t)(n0 + row) * HD + k0 + scol, &Bg[ldsoff], lane);
      stage16(wuE + (size_t)(n0 + row) * HD + k0 + scol, &Bu[ldsoff], lane);
    }
    __syncthreads();
    short8 af[4], bg[4], bu[4];
#pragma unroll
    for (int i = 0; i < 4; i++) {
      af[i] = *(const short8*)&As[(wm * 64 + i * 16 + frow) * BK + fk];
      bg[i] = *(const short8*)&Bg[(wn * 64 + i * 16 + frow) * BK + fk];
      bu[i] = *(const short8*)&Bu[(wn * 64 + i * 16 + frow) * BK + fk];
    }
#pragma unroll
    for (int i = 0; i < 4; i++)
#pragma unroll
      for (int j = 0; j < 4; j++) {
        accg[i][j] = __builtin_amdgcn_mfma_f32_16x16x32_bf16(af[i], bg[j], accg[i][j], 0, 0, 0);
        accu[i][j] = __builtin_amdgcn_mfma_f32_16x16x32_bf16(af[i], bu[j], accu[i][j], 0, 0, 0);
      }
  }

  int rb = wm * 64 + (lane >> 4) * 4;
  int cb = wn * 64 + (lane & 15);
#pragma unroll
  for (int i = 0; i < 4; i++)
#pragma unroll
    for (int r = 0; r < 4; r++) {
      int m = rb + i * 16 + r;
      if (m < rv) {
        ushort* hrow = h + (size_t)(m0 + m) * ID + n0 + cb;
#pragma unroll
        for (int j = 0; j < 4; j++) {
          float g = accg[i][j][r], u = accu[i][j][r];
          float hv = u * g / (1.0f + __expf(-g));
          hrow[j * 16] = f2bf(hv);
        }
      }
    }
}

// ---------------- down GEMM with row scatter ----------------
__global__ __launch_bounds__(256) void k_gemm_dn(const ushort* __restrict__ h,
                                                 const ushort* __restrict__ wd,
                                                 const int* __restrict__ cnt,
                                                 const int* __restrict__ perm,
                                                 float* __restrict__ out) {
  int e = blockIdx.x / MAXMT;
  int mt = blockIdx.x % MAXMT;
  int cnte = cnt[e];
  if (mt * BM >= cnte) return;
  int off = 0;
#pragma unroll
  for (int i = 0; i < NE; i++) off += (i < e) ? cnt[i] : 0;
  int m0 = off + mt * BM;
  int rv = cnte - mt * BM; if (rv > BM) rv = BM;
  int n0 = blockIdx.y * BN;

  __shared__ __align__(16) ushort As[BM * BK];
  __shared__ __align__(16) ushort Bs[BN * BK];

  int tid = threadIdx.x;
  int wv = tid >> 6, lane = tid & 63;
  int wm = wv >> 1, wn = wv & 1;
  f32x4 acc[4][4] = {};

  int srow0 = wv * 16 + (lane >> 2);
  int scol = (lane & 3) * 8;
  const ushort* wdE = wd + (size_t)e * HD * ID;
  int frow = lane & 15;
  int fk = (lane >> 4) * 8;

  for (int k0 = 0; k0 < ID; k0 += BK) {
    __syncthreads();
#pragma unroll
    for (int i = 0; i < 2; i++) {
      int row = i * 64 + srow0;
      int ldsoff = (i * 64 + wv * 16) * BK;
      stage16(h   + (size_t)(m0 + row) * ID + k0 + scol, &As[ldsoff], lane);
      stage16(wdE + (size_t)(n0 + row) * ID + k0 + scol, &Bs[ldsoff], lane);
    }
    __syncthreads();
    short8 af[4], bf[4];
#pragma unroll
    for (int i = 0; i < 4; i++) {
      af[i] = *(const short8*)&As[(wm * 64 + i * 16 + frow) * BK + fk];
      bf[i] = *(const short8*)&Bs[(wn * 64 + i * 16 + frow) * BK + fk];
    }
#pragma unroll
    for (int i = 0; i < 4; i++)
#pragma unroll
      for (int j = 0; j < 4; j++)
        acc[i][j] = __builtin_amdgcn_mfma_f32_16x16x32_bf16(af[i], bf[j], acc[i][j], 0, 0, 0);
  }

  int rb = wm * 64 + (lane >> 4) * 4;
  int cb = n0 + wn * 64 + (lane & 15);
#pragma unroll
  for (int i = 0; i < 4; i++)
#pragma unroll
    for (int r = 0; r < 4; r++) {
      int m = rb + i * 16 + r;
      if (m < rv) {
        int t = perm[m0 + m];
        float* orow = out + (size_t)t * HD + cb;
#pragma unroll
        for (int j = 0; j < 4; j++) orow[j * 16] = acc[i][j][r];
      }
    }
}

extern "C" void kernel_launch(void* const* d_in, const int* in_sizes, int n_in,
                              void* d_out, int out_size, void* d_ws, size_t ws_size,
                              hipStream_t stream) {
  const float* x     = (const float*)d_in[0];
  const float* gw    = (const float*)d_in[1];
  const float* wgate = (const float*)d_in[2];
  const float* wup   = (const float*)d_in[3];
  const float* wdown = (const float*)d_in[4];
  float* out = (float*)d_out;

  uint8_t* ws = (uint8_t*)d_ws;
  int*   cnt  = (int*)ws;                    // 8 ints
  int*   sel  = (int*)(ws + 256);
  int*   rank = sel + T_TOK;
  int*   perm = rank + T_TOK;
  float* rw   = (float*)(perm + T_TOK);
  size_t o = 256 + (size_t)4 * 4 * T_TOK;
  ushort* wg_b = (ushort*)(ws + o); o += (size_t)NE * ID * HD * 2;
  ushort* wu_b = (ushort*)(ws + o); o += (size_t)NE * ID * HD * 2;
  ushort* wd_b = (ushort*)(ws + o); o += (size_t)NE * HD * ID * 2;
  ushort* xs   = (ushort*)(ws + o); o += (size_t)(T_TOK + BM) * HD * 2;
  ushort* hbuf = (ushort*)(ws + o); o += (size_t)(T_TOK + BM) * ID * 2;

  k_router<<<T_TOK / 4, 256, 0, stream>>>(x, gw, sel, rw, cnt);
  k_count<<<T_TOK / 256, 256, 0, stream>>>(sel, cnt, rank);
  k_perm<<<T_TOK / 256, 256, 0, stream>>>(sel, cnt, rank, perm);
  k_gather<<<T_TOK, 256, 0, stream>>>(x, rw, perm, xs);
  k_cast<<<(NE * ID * HD / 4) / 256, 256, 0, stream>>>(
      (const float4*)wgate, (const float4*)wup, (const float4*)wdown,
      (ushort4*)wg_b, (ushort4*)wu_b, (ushort4*)wd_b);
  k_gemm_gu<<<dim3(NE * MAXMT, ID / BN), 256, 0, stream>>>(xs, wg_b, wu_b, cnt, hbuf);
  k_gemm_dn<<<dim3(NE * MAXMT, HD / BN), 256, 0, stream>>>(hbuf, wd_b, cnt, perm, out);
}

// Round 2
// 256.143 us; speedup vs baseline: 1.4578x; 1.4578x over previous
//
#include <hip/hip_runtime.h>
#include <hip/hip_bf16.h>
#include <cstdint>
#include <cmath>

#define T_TOK 8192
#define HD 1024
#define ID 512
#define NE 8
#define BM 128
#define BN 64
#define BK 32
#define MAXMT (T_TOK / BM)   // 64

#define GU_NT (ID / BN)            // 8
#define GU_MAXID (MAXMT * NE * GU_NT)   // 4096
#define DN_NT (HD / BN)            // 16
#define DN_MAXID (MAXMT * NE * DN_NT)   // 8192
#define GU_GRID 768
#define DN_GRID 1280

typedef __attribute__((ext_vector_type(8))) short short8;
typedef __attribute__((ext_vector_type(4))) float f32x4;

__device__ __forceinline__ unsigned short f2bf(float f) {
  union { float f; unsigned int u; } v; v.f = f;
  unsigned int u = v.u;
  u += 0x7fffu + ((u >> 16) & 1u);   // RNE
  return (unsigned short)(u >> 16);
}

#if __has_builtin(__builtin_amdgcn_global_load_lds)
#define HAVE_GLDS 1
#endif

// Global->LDS 16B/lane stage. Async path: LDS dest is wave-uniform base + lane*16.
__device__ __forceinline__ void stage16(const ushort* __restrict__ g,
                                        ushort* lds_wave_base, int lane) {
#ifdef HAVE_GLDS
  __builtin_amdgcn_global_load_lds((const __attribute__((address_space(1))) void*)g,
                                   (__attribute__((address_space(3))) void*)lds_wave_base,
                                   16, 0, 0);
#else
  *(uint4*)(lds_wave_base + (size_t)lane * 8) = *(const uint4*)g;
#endif
}

// Stage one 16-row x BK chunk with XOR column-group swizzle:
// LDS[row][cg] holds global colgroup (cg ^ ((row>>1)&3)). Global access per row is
// still the same contiguous 64B, lanes permuted within it (coalescing unchanged).
__device__ __forceinline__ void stageRowSw(const ushort* __restrict__ rowbase, size_t ld,
                                           int k0, ushort* ldsChunk, int lane) {
  int rl = lane >> 2;
  int sw = (lane & 3) ^ ((rl >> 1) & 3);
  stage16(rowbase + (size_t)rl * ld + k0 + sw * 8, ldsChunk, lane);
}

// Read an 8-element bf16 A/B fragment at (local row, global colgroup gcg), undoing swizzle.
__device__ __forceinline__ short8 fragSw(const ushort* buf, int row, int gcg) {
  int cg = gcg ^ ((row >> 1) & 3);
  return *(const short8*)&buf[row * BK + cg * 8];
}

// ---------------- router: logits, argmax, sigmoid ----------------
__global__ __launch_bounds__(256) void k_router(const float* __restrict__ x,
                                                const float* __restrict__ gw,
                                                int* __restrict__ sel,
                                                float* __restrict__ rw,
                                                int* __restrict__ cnt) {
  if (blockIdx.x == 0 && threadIdx.x < NE) cnt[threadIdx.x] = 0;
  int wv = threadIdx.x >> 6, lane = threadIdx.x & 63;
  int t = blockIdx.x * 4 + wv;
  const float4* xr = (const float4*)(x + (size_t)t * HD);
  double acc[NE];
#pragma unroll
  for (int e = 0; e < NE; e++) acc[e] = 0.0;
#pragma unroll
  for (int j = 0; j < 4; j++) {
    float4 xv = xr[lane + 64 * j];
#pragma unroll
    for (int e = 0; e < NE; e++) {
      float4 wv4 = ((const float4*)(gw + e * HD))[lane + 64 * j];
      acc[e] += (double)xv.x * wv4.x + (double)xv.y * wv4.y +
                (double)xv.z * wv4.z + (double)xv.w * wv4.w;
    }
  }
#pragma unroll
  for (int e = 0; e < NE; e++)
    for (int off = 32; off >= 1; off >>= 1)
      acc[e] += __shfl_xor(acc[e], off);
  if (lane == 0) {
    double best = acc[0]; int bi = 0;
#pragma unroll
    for (int e = 1; e < NE; e++) if (acc[e] > best) { best = acc[e]; bi = e; }
    sel[t] = bi;
    rw[t] = (float)(1.0 / (1.0 + exp(-best)));
  }
}

__global__ void k_count(const int* __restrict__ sel, int* __restrict__ cnt,
                        int* __restrict__ rank) {
  int t = blockIdx.x * 256 + threadIdx.x;
  rank[t] = atomicAdd(&cnt[sel[t]], 1);
}

__global__ void k_perm(const int* __restrict__ sel, const int* __restrict__ cnt,
                       const int* __restrict__ rank, int* __restrict__ perm) {
  int t = blockIdx.x * 256 + threadIdx.x;
  int s = sel[t];
  int off = 0;
#pragma unroll
  for (int e = 0; e < NE; e++) off += (e < s) ? cnt[e] : 0;
  perm[off + rank[t]] = t;
}

// gather + routing-weight scale + fp32->bf16
__global__ __launch_bounds__(256) void k_gather(const float* __restrict__ x,
                                                const float* __restrict__ rw,
                                                const int* __restrict__ perm,
                                                ushort* __restrict__ xs) {
  int p = blockIdx.x;
  int t = perm[p];
  float s = rw[t];
  const float4* src = (const float4*)(x + (size_t)t * HD);
  ushort4* dst = (ushort4*)(xs + (size_t)p * HD);
  float4 v = src[threadIdx.x];
  ushort4 o;
  o.x = f2bf(v.x * s); o.y = f2bf(v.y * s); o.z = f2bf(v.z * s); o.w = f2bf(v.w * s);
  dst[threadIdx.x] = o;
}

// cast all three expert weight tensors fp32->bf16
__global__ __launch_bounds__(256) void k_cast(const float4* __restrict__ a,
                                              const float4* __restrict__ b,
                                              const float4* __restrict__ c,
                                              ushort4* __restrict__ oa,
                                              ushort4* __restrict__ ob,
                                              ushort4* __restrict__ oc) {
  int i = blockIdx.x * 256 + threadIdx.x;
  float4 v; ushort4 r;
  v = a[i]; r.x = f2bf(v.x); r.y = f2bf(v.y); r.z = f2bf(v.z); r.w = f2bf(v.w); oa[i] = r;
  v = b[i]; r.x = f2bf(v.x); r.y = f2bf(v.y); r.z = f2bf(v.z); r.w = f2bf(v.w); ob[i] = r;
  v = c[i]; r.x = f2bf(v.x); r.y = f2bf(v.y); r.z = f2bf(v.z); r.w = f2bf(v.w); oc[i] = r;
}

// ---------------- fused gate+up GEMM -> h = u * silu(g) ----------------
// Persistent-strided over id = mt*(NE*GU_NT) + e*GU_NT + nt so active ids form a
// dense prefix (balanced experts -> ids 0..~511 all active) and spread uniformly.
__global__ __launch_bounds__(256) void k_gemm_gu(const ushort* __restrict__ xs,
                                                 const ushort* __restrict__ wg,
                                                 const ushort* __restrict__ wu,
                                                 const int* __restrict__ cnt,
                                                 ushort* __restrict__ h) {
  __shared__ __align__(16) ushort As[BM * BK];
  __shared__ __align__(16) ushort Bg[BN * BK];
  __shared__ __align__(16) ushort Bu[BN * BK];

  int tid = threadIdx.x;
  int wv = tid >> 6, lane = tid & 63;
  int wm = wv >> 1, wn = wv & 1;
  int frow = lane & 15, gcg = lane >> 4;

  for (int id = blockIdx.x; id < GU_MAXID; id += GU_GRID) {
    int mt = id >> 6;             // id / (NE*GU_NT)
    int e  = (id >> 3) & 7;
    int nt = id & 7;
    int cnte = cnt[e];
    if (mt * BM >= cnte) continue;
    int off = 0;
#pragma unroll
    for (int i = 0; i < NE; i++) off += (i < e) ? cnt[i] : 0;
    int m0 = off + mt * BM;
    int rv = cnte - mt * BM; if (rv > BM) rv = BM;
    int n0 = nt * BN;

    const ushort* aBase = xs + (size_t)m0 * HD;
    const ushort* gBase = wg + (size_t)e * ID * HD + (size_t)n0 * HD;
    const ushort* uBase = wu + (size_t)e * ID * HD + (size_t)n0 * HD;

    f32x4 accg[4][2] = {};
    f32x4 accu[4][2] = {};

    for (int k0 = 0; k0 < HD; k0 += BK) {
      __syncthreads();
      stageRowSw(aBase + (size_t)(wv * 16) * HD,      HD, k0, &As[(wv * 16) * BK],      lane);
      stageRowSw(aBase + (size_t)(64 + wv * 16) * HD, HD, k0, &As[(64 + wv * 16) * BK], lane);
      stageRowSw(gBase + (size_t)(wv * 16) * HD,      HD, k0, &Bg[(wv * 16) * BK],      lane);
      stageRowSw(uBase + (size_t)(wv * 16) * HD,      HD, k0, &Bu[(wv * 16) * BK],      lane);
      __syncthreads();
      short8 af[4], bg[2], bu[2];
#pragma unroll
      for (int i = 0; i < 4; i++) af[i] = fragSw(As, wm * 64 + i * 16 + frow, gcg);
#pragma unroll
      for (int j = 0; j < 2; j++) {
        bg[j] = fragSw(Bg, wn * 32 + j * 16 + frow, gcg);
        bu[j] = fragSw(Bu, wn * 32 + j * 16 + frow, gcg);
      }
#pragma unroll
      for (int i = 0; i < 4; i++)
#pragma unroll
        for (int j = 0; j < 2; j++) {
          accg[i][j] = __builtin_amdgcn_mfma_f32_16x16x32_bf16(af[i], bg[j], accg[i][j], 0, 0, 0);
          accu[i][j] = __builtin_amdgcn_mfma_f32_16x16x32_bf16(af[i], bu[j], accu[i][j], 0, 0, 0);
        }
    }

    int rb = wm * 64 + (lane >> 4) * 4;
    int cb = n0 + wn * 32 + (lane & 15);
#pragma unroll
    for (int i = 0; i < 4; i++)
#pragma unroll
      for (int r = 0; r < 4; r++) {
        int m = rb + i * 16 + r;
        if (m < rv) {
          ushort* hrow = h + (size_t)(m0 + m) * ID + cb;
#pragma unroll
          for (int j = 0; j < 2; j++) {
            float g = accg[i][j][r], u = accu[i][j][r];
            float hv = u * g / (1.0f + __expf(-g));
            hrow[j * 16] = f2bf(hv);
          }
        }
      }
    __syncthreads();  // protect LDS before next tile's first stage
  }
}

// ---------------- down GEMM with row scatter ----------------
__global__ __launch_bounds__(256) void k_gemm_dn(const ushort* __restrict__ h,
                                                 const ushort* __restrict__ wd,
                                                 const int* __restrict__ cnt,
                                                 const int* __restrict__ perm,
                                                 float* __restrict__ out) {
  __shared__ __align__(16) ushort As[BM * BK];
  __shared__ __align__(16) ushort Bs[BN * BK];

  int tid = threadIdx.x;
  int wv = tid >> 6, lane = tid & 63;
  int wm = wv >> 1, wn = wv & 1;
  int frow = lane & 15, gcg = lane >> 4;

  for (int id = blockIdx.x; id < DN_MAXID; id += DN_GRID) {
    int mt = id >> 7;             // id / (NE*DN_NT)
    int e  = (id >> 4) & 7;
    int nt = id & 15;
    int cnte = cnt[e];
    if (mt * BM >= cnte) continue;
    int off = 0;
#pragma unroll
    for (int i = 0; i < NE; i++) off += (i < e) ? cnt[i] : 0;
    int m0 = off + mt * BM;
    int rv = cnte - mt * BM; if (rv > BM) rv = BM;
    int n0 = nt * BN;

    const ushort* aBase = h + (size_t)m0 * ID;
    const ushort* bBase = wd + (size_t)e * HD * ID + (size_t)n0 * ID;

    f32x4 acc[4][2] = {};

    for (int k0 = 0; k0 < ID; k0 += BK) {
      __syncthreads();
      stageRowSw(aBase + (size_t)(wv * 16) * ID,      ID, k0, &As[(wv * 16) * BK],      lane);
      stageRowSw(aBase + (size_t)(64 + wv * 16) * ID, ID, k0, &As[(64 + wv * 16) * BK], lane);
      stageRowSw(bBase + (size_t)(wv * 16) * ID,      ID, k0, &Bs[(wv * 16) * BK],      lane);
      __syncthreads();
      short8 af[4], bf[2];
#pragma unroll
      for (int i = 0; i < 4; i++) af[i] = fragSw(As, wm * 64 + i * 16 + frow, gcg);
#pragma unroll
      for (int j = 0; j < 2; j++) bf[j] = fragSw(Bs, wn * 32 + j * 16 + frow, gcg);
#pragma unroll
      for (int i = 0; i < 4; i++)
#pragma unroll
        for (int j = 0; j < 2; j++)
          acc[i][j] = __builtin_amdgcn_mfma_f32_16x16x32_bf16(af[i], bf[j], acc[i][j], 0, 0, 0);
    }

    int rb = wm * 64 + (lane >> 4) * 4;
    int cb = n0 + wn * 32 + (lane & 15);
#pragma unroll
    for (int i = 0; i < 4; i++)
#pragma unroll
      for (int r = 0; r < 4; r++) {
        int m = rb + i * 16 + r;
        if (m < rv) {
          int t = perm[m0 + m];
          float* orow = out + (size_t)t * HD + cb;
#pragma unroll
          for (int j = 0; j < 2; j++) orow[j * 16] = acc[i][j][r];
        }
      }
    __syncthreads();  // protect LDS before next tile's first stage
  }
}

extern "C" void kernel_launch(void* const* d_in, const int* in_sizes, int n_in,
                              void* d_out, int out_size, void* d_ws, size_t ws_size,
                              hipStream_t stream) {
  const float* x     = (const float*)d_in[0];
  const float* gw    = (const float*)d_in[1];
  const float* wgate = (const float*)d_in[2];
  const float* wup   = (const float*)d_in[3];
  const float* wdown = (const float*)d_in[4];
  float* out = (float*)d_out;

  uint8_t* ws = (uint8_t*)d_ws;
  int*   cnt  = (int*)ws;                    // 8 ints
  int*   sel  = (int*)(ws + 256);
  int*   rank = sel + T_TOK;
  int*   perm = rank + T_TOK;
  float* rw   = (float*)(perm + T_TOK);
  size_t o = 256 + (size_t)4 * 4 * T_TOK;
  ushort* wg_b = (ushort*)(ws + o); o += (size_t)NE * ID * HD * 2;
  ushort* wu_b = (ushort*)(ws + o); o += (size_t)NE * ID * HD * 2;
  ushort* wd_b = (ushort*)(ws + o); o += (size_t)NE * HD * ID * 2;
  ushort* xs   = (ushort*)(ws + o); o += (size_t)(T_TOK + BM) * HD * 2;
  ushort* hbuf = (ushort*)(ws + o); o += (size_t)(T_TOK + BM) * ID * 2;

  k_router<<<T_TOK / 4, 256, 0, stream>>>(x, gw, sel, rw, cnt);
  k_count<<<T_TOK / 256, 256, 0, stream>>>(sel, cnt, rank);
  k_perm<<<T_TOK / 256, 256, 0, stream>>>(sel, cnt, rank, perm);
  k_gather<<<T_TOK, 256, 0, stream>>>(x, rw, perm, xs);
  k_cast<<<(NE * ID * HD / 4) / 256, 256, 0, stream>>>(
      (const float4*)wgate, (const float4*)wup, (const float4*)wdown,
      (ushort4*)wg_b, (ushort4*)wu_b, (ushort4*)wd_b);
  k_gemm_gu<<<GU_GRID, 256, 0, stream>>>(xs, wg_b, wu_b, cnt, hbuf);
  k_gemm_dn<<<DN_GRID, 256, 0, stream>>>(hbuf, wd_b, cnt, perm, out);
}